// Round 1
// baseline (713.400 us; speedup 1.0000x reference)
//
#include <hip/hip_runtime.h>
#include <math.h>

#define B 256
#define LC 400
#define LQ 50
#define D 128

// ---------------------------------------------------------------------------
// Kernel 1: raw scores S[b,c,q] = (x_cont[b,c,:]*W2) . x_ques[b,q,:]
//                                 + x_cont[b,c,:].W0 + x_ques[b,q,:].W1
// Written into the S_bar region of d_out (raw; softmaxed later in place).
// Block: 256 threads, handles one b and a 32-row c-tile.
// LDS rows padded to 132 floats so the 8c x 8q lane grid reads ds_read_b128
// conflict-free (8 distinct bank-sets, 8-lane broadcast within a set).
// ---------------------------------------------------------------------------
#define CT1 32
__global__ __launch_bounds__(256) void k_scores(
    const float* __restrict__ xc_g, const float* __restrict__ xq_g,
    const float* __restrict__ W0, const float* __restrict__ W1,
    const float* __restrict__ W2, float* __restrict__ S_raw)
{
    __shared__ __align__(16) float xq[LQ * 132];
    __shared__ __align__(16) float xc[CT1 * 132];
    __shared__ float w[3 * D];
    __shared__ float sc[CT1], sq[LQ];

    const int b = blockIdx.y;
    const int c0 = blockIdx.x * CT1;
    const int t = threadIdx.x;
    const int nc = min(CT1, LC - c0);

    const float* xqb = xq_g + b * LQ * D;
    for (int i = t; i < LQ * D; i += 256) xq[(i >> 7) * 132 + (i & 127)] = xqb[i];
    const float* xcb = xc_g + (b * LC + c0) * D;
    for (int i = t; i < nc * D; i += 256) xc[(i >> 7) * 132 + (i & 127)] = xcb[i];
    if (t < D) { w[t] = W0[t]; w[D + t] = W1[t]; w[2 * D + t] = W2[t]; }
    __syncthreads();

    // per-row / per-col bias terms (use raw xc before premultiply)
    if (t < nc) {
        float a = 0.f;
        for (int d = 0; d < D; ++d) a += xc[t * 132 + d] * w[d];
        sc[t] = a;
    } else if (t >= 64 && t < 64 + LQ) {
        const int q = t - 64;
        float a = 0.f;
        for (int d = 0; d < D; ++d) a += xq[q * 132 + d] * w[D + d];
        sq[q] = a;
    }
    __syncthreads();
    for (int i = t; i < nc * D; i += 256) xc[(i >> 7) * 132 + (i & 127)] *= w[2 * D + (i & 127)];
    __syncthreads();

    const int wave = t >> 6, lane = t & 63;
    const int ql = lane & 7, cl = lane >> 3;
    // wave w owns c-tile w (8 rows), iterates 7 q-tiles of 8
    const int c = wave * 8 + cl;
    for (int qt = 0; qt < 7; ++qt) {
        const int q = qt * 8 + ql;
        if (c < nc && q < LQ) {
            const float4* xcv = (const float4*)(xc + c * 132);
            const float4* xqv = (const float4*)(xq + q * 132);
            float a = 0.f;
#pragma unroll
            for (int d = 0; d < D / 4; ++d) {
                float4 u = xcv[d], v = xqv[d];
                a += u.x * v.x + u.y * v.y + u.z * v.z + u.w * v.w;
            }
            S_raw[(b * LC + c0 + c) * LQ + q] = a + sc[c] + sq[q];
        }
    }
}

// ---------------------------------------------------------------------------
// Kernel 2: column softmax over c (masked by cont_len), written transposed to
// S_T[b,q,c]. One block per b. Reads raw S (must run BEFORE row softmax).
// ---------------------------------------------------------------------------
__global__ __launch_bounds__(256) void k_softmax_col(
    const float* __restrict__ S_raw, const int* __restrict__ cont_len,
    float* __restrict__ S_T)
{
    const int b = blockIdx.x;
    const int t = threadIdx.x;
    const int clen = cont_len[b];
    __shared__ float red[4][64];
    __shared__ float colmax[64], colinv[64];
    __shared__ float tile[LQ][65];

    const int q = t & 63, r = t >> 6;
    const float* Sb = S_raw + b * LC * LQ;

    // pass 1: max over valid c
    float m = -INFINITY;
    if (q < LQ) {
        const int cend = min((r + 1) * 100, clen);
        for (int c = r * 100; c < cend; ++c) m = fmaxf(m, Sb[c * LQ + q]);
    }
    red[r][q] = m;
    __syncthreads();
    if (r == 0) colmax[q] = fmaxf(fmaxf(red[0][q], red[1][q]), fmaxf(red[2][q], red[3][q]));
    __syncthreads();

    // pass 2: sum of exp over valid c
    float sum = 0.f;
    if (q < LQ) {
        const float cm = colmax[q];
        const int cend = min((r + 1) * 100, clen);
        for (int c = r * 100; c < cend; ++c) sum += __expf(Sb[c * LQ + q] - cm);
    }
    red[r][q] = sum;
    __syncthreads();
    if (r == 0) colinv[q] = 1.f / (red[0][q] + red[1][q] + red[2][q] + red[3][q]);
    __syncthreads();

    // pass 3: transpose-tile and write S_T coalesced
    float* STb = S_T + b * LQ * LC;
    for (int c0 = 0; c0 < LC; c0 += 64) {
        const int n = min(64, LC - c0);
        for (int i = t; i < n * LQ; i += 256) {
            const int cc = i / LQ, qq = i % LQ;
            tile[qq][cc] = Sb[(c0 + cc) * LQ + qq];
        }
        __syncthreads();
        for (int i = t; i < LQ * n; i += 256) {
            const int qq = i / n, cc = i % n;
            const int c = c0 + cc;
            const float v = (c < clen) ? __expf(tile[qq][cc] - colmax[qq]) * colinv[qq] : 0.f;
            STb[qq * LC + c] = v;
        }
        __syncthreads();
    }
}

// ---------------------------------------------------------------------------
// Kernel 3: row softmax over q (masked by ques_len), IN PLACE on raw S ->
// S_bar. One thread per (b,c) row. NOTE: no __restrict__ (read/write alias).
// ---------------------------------------------------------------------------
__global__ __launch_bounds__(256) void k_softmax_row(
    float* S, const int* __restrict__ ques_len)
{
    const int row = blockIdx.x * 256 + threadIdx.x;  // b*LC + c
    const int b = row / LC;
    const int qlen = ques_len[b];
    float* s = S + row * LQ;
    float m = -INFINITY;
    for (int qq = 0; qq < qlen; ++qq) m = fmaxf(m, s[qq]);
    float sum = 0.f;
    for (int qq = 0; qq < qlen; ++qq) sum += __expf(s[qq] - m);
    const float inv = 1.f / sum;
    for (int qq = 0; qq < LQ; ++qq) {
        const float v = (qq < qlen) ? __expf(s[qq] - m) * inv : 0.f;
        s[qq] = v;
    }
}

// ---------------------------------------------------------------------------
// Kernel 4: T[b,q,:] = S_T[b,q,:] @ x_cont[b]   (B*LQ blocks x 128 threads)
// ---------------------------------------------------------------------------
__global__ __launch_bounds__(128) void k_qc(
    const float* __restrict__ S_T, const float* __restrict__ xc_g,
    float* __restrict__ T)
{
    const int bq = blockIdx.x;
    const int b = bq / LQ;
    __shared__ float s[LC];
    const int t = threadIdx.x;
    const float* st = S_T + bq * LC;
    for (int i = t; i < LC; i += 128) s[i] = st[i];
    __syncthreads();
    const float* xc = xc_g + b * LC * D + t;
    float a0 = 0.f, a1 = 0.f;
    for (int c = 0; c < LC; c += 2) {
        a0 += s[c] * xc[c * D];
        a1 += s[c + 1] * xc[(c + 1) * D];
    }
    T[bq * D + t] = a0 + a1;
}

// ---------------------------------------------------------------------------
// Kernel 5: final concat output. One block per (b,c), 128 threads (d).
// out[b,c,:] = [xc, c2q, xc*c2q, xc*q2c]
// ---------------------------------------------------------------------------
__global__ __launch_bounds__(128) void k_out(
    const float* __restrict__ S_bar, const float* __restrict__ xq_g,
    const float* __restrict__ Tm, const float* __restrict__ xc_g,
    float* __restrict__ out)
{
    const int bc = blockIdx.x;
    const int b = bc / LC;
    __shared__ float s[LQ];
    const int t = threadIdx.x;
    if (t < LQ) s[t] = S_bar[bc * LQ + t];
    __syncthreads();
    const float* xq = xq_g + b * LQ * D + t;
    const float* Tb = Tm + b * LQ * D + t;
    float c2q = 0.f, q2c = 0.f;
#pragma unroll 5
    for (int q = 0; q < LQ; ++q) {
        const float wq = s[q];
        c2q += wq * xq[q * D];
        q2c += wq * Tb[q * D];
    }
    const float xc = xc_g[bc * D + t];
    float* o = out + (size_t)bc * (4 * D);
    o[t] = xc;
    o[D + t] = c2q;
    o[2 * D + t] = xc * c2q;
    o[3 * D + t] = xc * q2c;
}

// ---------------------------------------------------------------------------
extern "C" void kernel_launch(void* const* d_in, const int* in_sizes, int n_in,
                              void* d_out, int out_size, void* d_ws, size_t ws_size,
                              hipStream_t stream)
{
    (void)in_sizes; (void)n_in; (void)out_size; (void)ws_size;
    const float* x_cont = (const float*)d_in[0];
    const float* x_ques = (const float*)d_in[1];
    const float* W0 = (const float*)d_in[2];
    const float* W1 = (const float*)d_in[3];
    const float* W2 = (const float*)d_in[4];
    const int* cont_len = (const int*)d_in[5];
    const int* ques_len = (const int*)d_in[6];

    float* out = (float*)d_out;
    float* out_res  = out;                                  // B*LC*4D
    float* out_Sbar = out + (size_t)B * LC * 4 * D;         // B*LC*LQ
    float* out_ST   = out_Sbar + (size_t)B * LC * LQ;       // B*LQ*LC
    float* Tws = (float*)d_ws;                              // B*LQ*D floats

    // 1) raw S into the S_bar output region
    k_scores<<<dim3((LC + CT1 - 1) / CT1, B), 256, 0, stream>>>(
        x_cont, x_ques, W0, W1, W2, out_Sbar);
    // 2) column softmax (reads raw S) -> S_T
    k_softmax_col<<<B, 256, 0, stream>>>(out_Sbar, cont_len, out_ST);
    // 3) row softmax in place -> S_bar
    k_softmax_row<<<(B * LC) / 256, 256, 0, stream>>>(out_Sbar, ques_len);
    // 4) T = S_T @ x_cont
    k_qc<<<B * LQ, 128, 0, stream>>>(out_ST, x_cont, Tws);
    // 5) fused output concat
    k_out<<<B * LC, 128, 0, stream>>>(out_Sbar, x_ques, Tws, x_cont, out_res);
}

// Round 2
// 440.058 us; speedup vs baseline: 1.6211x; 1.6211x over previous
//
#include <hip/hip_runtime.h>
#include <math.h>

#define B 256
#define LC 400
#define LQ 50
#define D 128

// ---------------------------------------------------------------------------
// Kernel 1: raw scores S[b,c,q] = (x_cont*W2).x_ques + xc.W0 + xq.W1
// Grid (7 c-tiles, B), block 256. Per-thread 2c x 7q register tile.
// LDS rows padded to 132 floats (528 B = 33x16) for aligned b128 reads.
// ---------------------------------------------------------------------------
#define CT 64
__global__ __launch_bounds__(256) void k_scores(
    const float* __restrict__ xc_g, const float* __restrict__ xq_g,
    const float* __restrict__ W0, const float* __restrict__ W1,
    const float* __restrict__ W2, float* __restrict__ S_raw)
{
    __shared__ __align__(16) float xq[56 * 132];   // 56 q rows (8 groups x 7)
    __shared__ __align__(16) float xc[CT * 132];
    __shared__ float w[3 * D];
    __shared__ float sc[CT], sq[64];
    __shared__ float sS[CT * 51];

    const int b = blockIdx.y;
    const int c0 = blockIdx.x * CT;
    const int t = threadIdx.x;
    const int nc = min(CT, LC - c0);

    const float* xqb = xq_g + b * LQ * D;
    for (int i = t; i < LQ * D; i += 256) xq[(i >> 7) * 132 + (i & 127)] = xqb[i];
    const float* xcb = xc_g + (size_t)(b * LC + c0) * D;
    for (int i = t; i < nc * D; i += 256) xc[(i >> 7) * 132 + (i & 127)] = xcb[i];
    if (t < D) { w[t] = W0[t]; w[D + t] = W1[t]; w[2 * D + t] = W2[t]; }
    __syncthreads();

    // bias terms from raw xc / xq
    if (t < nc) {
        const float4* r = (const float4*)(xc + t * 132);
        float4 a = {0.f, 0.f, 0.f, 0.f};
        const float4* wv = (const float4*)w;
        for (int d = 0; d < D / 4; ++d) {
            float4 u = r[d], vv = wv[d];
            a.x += u.x * vv.x; a.y += u.y * vv.y; a.z += u.z * vv.z; a.w += u.w * vv.w;
        }
        sc[t] = a.x + a.y + a.z + a.w;
    } else if (t >= 64 && t < 64 + LQ) {
        const int q = t - 64;
        const float4* r = (const float4*)(xq + q * 132);
        const float4* wv = (const float4*)(w + D);
        float4 a = {0.f, 0.f, 0.f, 0.f};
        for (int d = 0; d < D / 4; ++d) {
            float4 u = r[d], vv = wv[d];
            a.x += u.x * vv.x; a.y += u.y * vv.y; a.z += u.z * vv.z; a.w += u.w * vv.w;
        }
        sq[q] = a.x + a.y + a.z + a.w;
    }
    __syncthreads();
    for (int i = t; i < nc * D; i += 256) xc[(i >> 7) * 132 + (i & 127)] *= w[2 * D + (i & 127)];
    __syncthreads();

    // compute: qg = t&7 owns q = qg*7+j (j<7); cg = t>>3 owns c = 2cg, 2cg+1
    const int qg = t & 7, cg = t >> 3;
    const int cA = cg * 2;
    if (cA < nc) {
        float accA[7] = {0, 0, 0, 0, 0, 0, 0};
        float accB[7] = {0, 0, 0, 0, 0, 0, 0};
        const float4* xc4 = (const float4*)xc;
        const float4* xq4 = (const float4*)xq;
#pragma unroll 8
        for (int d4 = 0; d4 < 32; ++d4) {
            const float4 a0 = xc4[cA * 33 + d4];
            const float4 a1 = xc4[(cA + 1) * 33 + d4];
#pragma unroll
            for (int j = 0; j < 7; ++j) {
                const float4 bq = xq4[(qg * 7 + j) * 33 + d4];
                accA[j] += a0.x * bq.x + a0.y * bq.y + a0.z * bq.z + a0.w * bq.w;
                accB[j] += a1.x * bq.x + a1.y * bq.y + a1.z * bq.z + a1.w * bq.w;
            }
        }
#pragma unroll
        for (int j = 0; j < 7; ++j) {
            const int q = qg * 7 + j;
            if (q < LQ) {
                sS[cA * 51 + q] = accA[j];
                sS[(cA + 1) * 51 + q] = accB[j];
            }
        }
    }
    __syncthreads();

    float* Sb = S_raw + (size_t)(b * LC + c0) * LQ;
    for (int i = t; i < nc * LQ; i += 256) {
        const int c = i / LQ, q = i % LQ;
        Sb[i] = sS[c * 51 + q] + sc[c] + sq[q];
    }
}

// ---------------------------------------------------------------------------
// Kernel 2: fused dual softmax. One block per b, S resident in LDS.
// Row softmax (over q, mask ques_len) -> S_bar (in place over S_raw).
// Col softmax (over c, mask cont_len) -> S_T transposed, coalesced.
// ---------------------------------------------------------------------------
__global__ __launch_bounds__(512) void k_softmax_fused(
    float* S_inout, const int* __restrict__ cont_len,
    const int* __restrict__ ques_len, float* __restrict__ S_T)
{
    __shared__ float sS[LC * 53];       // pad 53 (odd) -> conflict-free strides
    __shared__ float red[512];
    __shared__ float colmax[64], colinv[64];
    __shared__ float rowmax[LC], rowinv[LC];

    const int b = blockIdx.x;
    const int t = threadIdx.x;
    const int clen = cont_len[b];
    const int qlen = ques_len[b];
    float* Sb = S_inout + (size_t)b * LC * LQ;

    for (int i = t; i < LC * LQ; i += 512) sS[(i / LQ) * 53 + (i % LQ)] = Sb[i];
    __syncthreads();

    // column stats (over c < clen) : thread (q = t%50, r = t/50), r<10
    const int q = t % LQ, r = t / LQ;
    if (r < 10) {
        float m = -INFINITY;
        const int cend = min((r + 1) * 40, clen);
        for (int c = r * 40; c < cend; ++c) m = fmaxf(m, sS[c * 53 + q]);
        red[r * LQ + q] = m;
    }
    __syncthreads();
    if (t < LQ) {
        float m = red[t];
        for (int rr = 1; rr < 10; ++rr) m = fmaxf(m, red[rr * LQ + t]);
        colmax[t] = m;
    }
    __syncthreads();
    if (r < 10) {
        float s = 0.f;
        const float cm = colmax[q];
        const int cend = min((r + 1) * 40, clen);
        for (int c = r * 40; c < cend; ++c) s += __expf(sS[c * 53 + q] - cm);
        red[r * LQ + q] = s;
    }
    __syncthreads();
    if (t < LQ) {
        float s = 0.f;
        for (int rr = 0; rr < 10; ++rr) s += red[rr * LQ + t];
        colinv[t] = 1.f / s;
    }
    // row stats (over q < qlen) : thread = c
    if (t < LC) {
        float m = -INFINITY;
        for (int qq = 0; qq < qlen; ++qq) m = fmaxf(m, sS[t * 53 + qq]);
        float s = 0.f;
        for (int qq = 0; qq < qlen; ++qq) s += __expf(sS[t * 53 + qq] - m);
        rowmax[t] = m;
        rowinv[t] = 1.f / s;
    }
    __syncthreads();

    // S_bar write (coalesced, in place)
    for (int i = t; i < LC * LQ; i += 512) {
        const int c = i / LQ, qq = i % LQ;
        const float v = (qq < qlen) ? __expf(sS[c * 53 + qq] - rowmax[c]) * rowinv[c] : 0.f;
        Sb[i] = v;
    }
    // S_T write (coalesced, transposed)
    float* STb = S_T + (size_t)b * LQ * LC;
    for (int i = t; i < LQ * LC; i += 512) {
        const int qq = i / LC, c = i % LC;
        const float v = (c < clen) ? __expf(sS[c * 53 + qq] - colmax[qq]) * colinv[qq] : 0.f;
        STb[i] = v;
    }
}

// ---------------------------------------------------------------------------
// Kernel 3: T[b] = S_T[b] @ x_cont[b]   (50x400 @ 400x128). One block per b.
// S_T in LDS; xc streamed from global (L2). Per-thread 7q x 4d, 4c-unrolled.
// ---------------------------------------------------------------------------
__global__ __launch_bounds__(256) void k_qc(
    const float* __restrict__ S_T, const float* __restrict__ xc_g,
    float* __restrict__ T)
{
    __shared__ __align__(16) float sT[56 * 404];   // rows padded: 404 fl = 101x16B

    const int b = blockIdx.x;
    const int t = threadIdx.x;
    const float* STb = S_T + (size_t)b * LQ * LC;
    for (int i = t; i < LQ * LC; i += 256) sT[(i / LC) * 404 + (i % LC)] = STb[i];
    __syncthreads();

    const int d4 = t & 31, qg = t >> 5;   // qg 0..7 owns q = qg*7+j
    float4 acc[7];
#pragma unroll
    for (int j = 0; j < 7; ++j) acc[j] = make_float4(0.f, 0.f, 0.f, 0.f);

    const float4* xcv = (const float4*)xc_g + (size_t)b * LC * 32 + d4;
    const float4* sT4 = (const float4*)sT;
    for (int c = 0; c < LC; c += 4) {
        const float4 x0 = xcv[(c + 0) * 32];
        const float4 x1 = xcv[(c + 1) * 32];
        const float4 x2 = xcv[(c + 2) * 32];
        const float4 x3 = xcv[(c + 3) * 32];
#pragma unroll
        for (int j = 0; j < 7; ++j) {
            const float4 wv = sT4[(qg * 7 + j) * 101 + (c >> 2)];
            acc[j].x += wv.x * x0.x + wv.y * x1.x + wv.z * x2.x + wv.w * x3.x;
            acc[j].y += wv.x * x0.y + wv.y * x1.y + wv.z * x2.y + wv.w * x3.y;
            acc[j].z += wv.x * x0.z + wv.y * x1.z + wv.z * x2.z + wv.w * x3.z;
            acc[j].w += wv.x * x0.w + wv.y * x1.w + wv.z * x2.w + wv.w * x3.w;
        }
    }
    float4* Tb = (float4*)T + (size_t)b * LQ * 32 + d4;
#pragma unroll
    for (int j = 0; j < 7; ++j) {
        const int qq = qg * 7 + j;
        if (qq < LQ) Tb[qq * 32] = acc[j];
    }
}

// ---------------------------------------------------------------------------
// Kernel 4: out[b,c,:] = [xc, c2q, xc*c2q, xc*q2c].
// Grid (7 c-tiles, B), block 256. xq/T/S_bar tile in LDS.
// Per-thread 8c x 4d register tile: 64 FMA per 2 ds_read_b128.
// ---------------------------------------------------------------------------
__global__ __launch_bounds__(256) void k_out(
    const float* __restrict__ S_bar, const float* __restrict__ xq_g,
    const float* __restrict__ Tm, const float* __restrict__ xc_g,
    float* __restrict__ out)
{
    __shared__ __align__(16) float xqL[LQ * 132];
    __shared__ __align__(16) float TL[LQ * 132];
    __shared__ float sbL[CT * 51];

    const int b = blockIdx.y;
    const int c0 = blockIdx.x * CT;
    const int t = threadIdx.x;
    const int nc = min(CT, LC - c0);

    const float* xqb = xq_g + (size_t)b * LQ * D;
    const float* Tb = Tm + (size_t)b * LQ * D;
    for (int i = t; i < LQ * D; i += 256) {
        xqL[(i >> 7) * 132 + (i & 127)] = xqb[i];
        TL[(i >> 7) * 132 + (i & 127)] = Tb[i];
    }
    const float* sb_g = S_bar + (size_t)(b * LC + c0) * LQ;
    for (int i = t; i < nc * LQ; i += 256) sbL[(i / LQ) * 51 + (i % LQ)] = sb_g[i];
    __syncthreads();

    const int d4 = t & 31, cg = t >> 5;   // cg 0..7 owns 8 c rows
    float4 c2q[8], q2c[8];
#pragma unroll
    for (int i = 0; i < 8; ++i) {
        c2q[i] = make_float4(0.f, 0.f, 0.f, 0.f);
        q2c[i] = make_float4(0.f, 0.f, 0.f, 0.f);
    }
    const float4* xq4 = (const float4*)xqL;
    const float4* T4 = (const float4*)TL;
    const int cbase = cg * 8;
    for (int qq = 0; qq < LQ; ++qq) {
        const float4 xv = xq4[qq * 33 + d4];
        const float4 tv = T4[qq * 33 + d4];
#pragma unroll
        for (int i = 0; i < 8; ++i) {
            const float wq = sbL[(cbase + i) * 51 + qq];
            c2q[i].x += wq * xv.x; c2q[i].y += wq * xv.y;
            c2q[i].z += wq * xv.z; c2q[i].w += wq * xv.w;
            q2c[i].x += wq * tv.x; q2c[i].y += wq * tv.y;
            q2c[i].z += wq * tv.z; q2c[i].w += wq * tv.w;
        }
    }

    const float4* xcv = (const float4*)xc_g;
    float4* out4 = (float4*)out;
#pragma unroll
    for (int i = 0; i < 8; ++i) {
        const int c = cbase + i;
        if (c < nc) {
            const int row = b * LC + c0 + c;
            const float4 xc = xcv[(size_t)row * 32 + d4];
            float4* o = out4 + (size_t)row * 128 + d4;
            o[0] = xc;
            o[32] = c2q[i];
            o[64] = make_float4(xc.x * c2q[i].x, xc.y * c2q[i].y,
                                xc.z * c2q[i].z, xc.w * c2q[i].w);
            o[96] = make_float4(xc.x * q2c[i].x, xc.y * q2c[i].y,
                                xc.z * q2c[i].z, xc.w * q2c[i].w);
        }
    }
}

// ---------------------------------------------------------------------------
extern "C" void kernel_launch(void* const* d_in, const int* in_sizes, int n_in,
                              void* d_out, int out_size, void* d_ws, size_t ws_size,
                              hipStream_t stream)
{
    (void)in_sizes; (void)n_in; (void)out_size; (void)ws_size;
    const float* x_cont = (const float*)d_in[0];
    const float* x_ques = (const float*)d_in[1];
    const float* W0 = (const float*)d_in[2];
    const float* W1 = (const float*)d_in[3];
    const float* W2 = (const float*)d_in[4];
    const int* cont_len = (const int*)d_in[5];
    const int* ques_len = (const int*)d_in[6];

    float* out = (float*)d_out;
    float* out_res  = out;                                  // B*LC*4D
    float* out_Sbar = out + (size_t)B * LC * 4 * D;         // B*LC*LQ
    float* out_ST   = out_Sbar + (size_t)B * LC * LQ;       // B*LQ*LC
    float* Tws = (float*)d_ws;                              // B*LQ*D floats

    k_scores<<<dim3(7, B), 256, 0, stream>>>(x_cont, x_ques, W0, W1, W2, out_Sbar);
    k_softmax_fused<<<B, 512, 0, stream>>>(out_Sbar, cont_len, ques_len, out_ST);
    k_qc<<<B, 256, 0, stream>>>(out_ST, x_cont, Tws);
    k_out<<<dim3(7, B), 256, 0, stream>>>(out_Sbar, x_ques, Tws, x_cont, out_res);
}